// Round 18
// baseline (372.898 us; speedup 1.0000x reference)
//
#include <hip/hip_runtime.h>
#include <hip/hip_bf16.h>
#include <stdint.h>

typedef __bf16 bf8 __attribute__((ext_vector_type(8)));
typedef float  f4  __attribute__((ext_vector_type(4)));

__device__ __forceinline__ unsigned f2bf(float f) {
  union { float f; unsigned u; } v; v.f = f;
  return (v.u + 0x7FFFu + ((v.u >> 16) & 1u)) >> 16;  // RNE f32->bf16
}

// async global->LDS, 16B/lane; LDS dest = wave-uniform base + lane*16
__device__ __forceinline__ void gload_lds16(const void* g, void* l) {
  __builtin_amdgcn_global_load_lds(
      (const __attribute__((address_space(1))) void*)(uintptr_t)g,
      (__attribute__((address_space(3))) void*)(uint32_t)(uintptr_t)l,
      16, 0, 0);
}

// ---------------- pass 1a: x f32 -> bf16 ----------------
__global__ void cvt_x(const float4* __restrict__ x, uint4* __restrict__ xb, int n16) {
  int i = blockIdx.x * blockDim.x + threadIdx.x;
  if (i >= n16) return;
  float4 f0 = x[2 * i], f1 = x[2 * i + 1];
  uint4 w;
  w.x = f2bf(f0.x) | (f2bf(f0.y) << 16);
  w.y = f2bf(f0.z) | (f2bf(f0.w) << 16);
  w.z = f2bf(f1.x) | (f2bf(f1.y) << 16);
  w.w = f2bf(f1.z) | (f2bf(f1.w) << 16);
  xb[i] = w;
}

// ---------------- pass 1b: dequant qweight -> W^T bf16 [N][K] ----------------
__global__ void dq_w(const int* __restrict__ qw, const int* __restrict__ qz,
                     const float* __restrict__ sc, unsigned short* __restrict__ wt,
                     int N, int K, int group_size) {
  int id = blockIdx.x * blockDim.x + threadIdx.x;  // N*K/64 threads
  int n  = id % N;
  int kb = id / N;                  // 64-k block
  if (kb >= K / 64) return;
  int g = (kb * 64) / group_size;
  unsigned zq = ((unsigned)qz[g * (N >> 3) + (n >> 3)] >> (4 * (n & 7))) & 0xFu;
  float zs = (float)(int)(zq + 1u);
  float s  = sc[(size_t)g * N + n];
  #pragma unroll
  for (int r = 0; r < 8; ++r) {
    unsigned q = (unsigned)qw[(size_t)(kb * 8 + r) * N + n];
    uint4 w;
    #pragma unroll
    for (int h = 0; h < 4; ++h) {
      float v0 = (float)(int)((q >> (8 * h))     & 0xFu) - zs;
      float v1 = (float)(int)((q >> (8 * h + 4)) & 0xFu) - zs;
      ((unsigned*)&w)[h] = f2bf(v0 * s) | (f2bf(v1 * s) << 16);
    }
    *(uint4*)(wt + (size_t)n * K + kb * 64 + r * 8) = w;
  }
}

// ---------------- pass 2: 128^2 bf16 GEMM, 4 waves, 2 blocks/CU (TLP) -------
// Diagnosis r5-r17: 256^2/8-wave/128KB-LDS = 1 block/CU; all waves are
// barrier-synced in ONE domain -> matrix pipe idles 46% and no intra-block
// schedule (9 variants, all 247-257us) can fill it. Fix: shrink the sync
// domain. 128^2 tile, 4 waves (64x64/wave), LDS dbuf = 64KB -> TWO blocks
// co-resident; when block A sits at its barrier/drain, block B's waves feed
// the MFMA pipe (m97's implicit-overlap mechanism, now with a conflict-free
// LDS layout and exact-write staging). Regs ~150 < 256 cap at (256,2) -> no
// r14-style spill. Simple 1-window/tile loop: the ~300cyc under-covered
// drain is exactly what the other block fills.
// LDS: 1024B subtiles (16 rows x 32 cols bf16), per-row chunk rotation
// (conflict-free b128, r4-verified; pre-permuted global source, rule #21).
#define BM 128
#define BN 128
#define BK 64

__launch_bounds__(256, 2)
__global__ void gemm_tlp2(const unsigned short* __restrict__ A,  // [M][K] bf16
                          const unsigned short* __restrict__ B,  // [N][K] bf16
                          const float* __restrict__ bias,
                          float* __restrict__ out,
                          int M, int N, int K) {
  __shared__ __align__(16) char smem[65536];   // 2 x (A 16KB + B 16KB)

  const int nbx = N / BN;
  const int nwg = (M / BM) * nbx;
  const int id  = blockIdx.y * gridDim.x + blockIdx.x;
  const int cpx = nwg >> 3;                       // nwg % 8 == 0 (2048)
  const int swzid = (id & 7) * cpx + (id >> 3);   // XCD-contiguous chunks
  const int m0 = (swzid / nbx) * BM;
  const int n0 = (swzid % nbx) * BN;

  const int t    = threadIdx.x;
  const int wid  = t >> 6, lane = t & 63;
  const int wr   = wid >> 1, wc = wid & 1;        // 2(M) x 2(N) waves, 64x64 each
  const int lr   = lane & 15, lk = lane >> 4;
  // permuted frag-read offset within a 1024B subtile (r4 rotation, conflict-free)
  const unsigned loff = (unsigned)(lr * 64 + (((lk + (lr >> 1)) & 3) << 4));

  const int srow = lane >> 2;                          // staging row in subtile
  const int scol = (((lane & 3) - (lane >> 3)) & 3) * 8;  // permuted src chunk

  f4 acc[4][4] = {};

  const int nK = K / BK;
  const int ra = wr * 4;   // A row-group base (4 groups = 64 rows)
  const int rb = wc * 4;   // B row-group base

  // A-tile 128x64 bf16 = 8 rowgroups x 2 colgroups of 1KB subtiles (16KB).
  // wave wid stages A rowgroups {2wid, 2wid+1} (both cg) + same for B
  // -> 8 gload_lds per thread per K-tile.
#define STAGE(tile)                                                               \
  {                                                                               \
    const int _tt = (tile);                                                       \
    char* _buf = smem + (_tt & 1) * 32768;                                        \
    _Pragma("unroll")                                                             \
    for (int sg = 0; sg < 2; ++sg) {                                              \
      const int _rg = wid * 2 + sg;                                               \
      _Pragma("unroll")                                                           \
      for (int cg = 0; cg < 2; ++cg) {                                            \
        gload_lds16(A + (size_t)(m0 + _rg * 16 + srow) * K + _tt * BK + cg * 32 + scol, \
                    _buf + ((_rg * 2 + cg) << 10));                               \
        gload_lds16(B + (size_t)(n0 + _rg * 16 + srow) * K + _tt * BK + cg * 32 + scol, \
                    _buf + 16384 + ((_rg * 2 + cg) << 10));                       \
      }                                                                           \
    }                                                                             \
  }
#define RD_A(buf, slot) (*(const bf8*)(smem + (buf) * 32768 + ((unsigned)(slot) << 10) + loff))
#define RD_B(buf, slot) (*(const bf8*)(smem + (buf) * 32768 + 16384 + ((unsigned)(slot) << 10) + loff))

  // Prologue: stage tile0; own-drain; barrier.
  STAGE(0);
  asm volatile("s_waitcnt vmcnt(0)" ::: "memory");
  __builtin_amdgcn_s_barrier();
  __builtin_amdgcn_sched_barrier(0);

  for (int kt = 0; kt < nK; ++kt) {
    const int buf = kt & 1;

    // stage next tile into other buffer (its readers drained last window)
    if (kt + 1 < nK) STAGE(kt + 1);

    __builtin_amdgcn_s_setprio(1);
    bf8 a[4][2], b[4][2];
    #pragma unroll
    for (int mi = 0; mi < 4; ++mi)
      #pragma unroll
      for (int ks = 0; ks < 2; ++ks)
        a[mi][ks] = RD_A(buf, (ra + mi) * 2 + ks);
    #pragma unroll
    for (int nj = 0; nj < 4; ++nj)
      #pragma unroll
      for (int ks = 0; ks < 2; ++ks)
        b[nj][ks] = RD_B(buf, (rb + nj) * 2 + ks);
    #pragma unroll
    for (int mi = 0; mi < 4; ++mi)
      #pragma unroll
      for (int nj = 0; nj < 4; ++nj)
        #pragma unroll
        for (int ks = 0; ks < 2; ++ks)
          acc[mi][nj] = __builtin_amdgcn_mfma_f32_16x16x32_bf16(a[mi][ks], b[nj][ks], acc[mi][nj], 0, 0, 0);
    __builtin_amdgcn_s_setprio(0);

    // own DMAs drained before rendezvous (vmcnt is per-wave); then barrier.
    // The ~300cyc residual stall here is filled by the co-resident block.
    asm volatile("s_waitcnt vmcnt(0)" ::: "memory");
    __builtin_amdgcn_s_barrier();
    __builtin_amdgcn_sched_barrier(0);
  }

  // ---- epilogue: C/D layout col=lane&15, row=(lane>>4)*4+reg ----
  #pragma unroll
  for (int nj = 0; nj < 4; ++nj) {
    int col = n0 + wc * 64 + nj * 16 + lr;
    float bv = bias[col];
    #pragma unroll
    for (int mi = 0; mi < 4; ++mi) {
      int row = m0 + wr * 64 + mi * 16 + lk * 4;
      #pragma unroll
      for (int r = 0; r < 4; ++r)
        out[(size_t)(row + r) * N + col] = acc[mi][nj][r] + bv;
    }
  }
#undef STAGE
#undef RD_A
#undef RD_B
}

// ---------------- fallback (ws too small): round-1 fused kernel ----------------
#define FBM 128
#define FBN 128
#define FBK 64
__launch_bounds__(256, 2)
__global__ void woq_gemm(const float* __restrict__ x,
                         const int*   __restrict__ qweight,
                         const int*   __restrict__ qzeros,
                         const float* __restrict__ scales,
                         const float* __restrict__ bias,
                         float*       __restrict__ out,
                         int M, int N, int K) {
  __shared__ unsigned short sA[FBM * FBK];
  __shared__ unsigned short sB[FBN * FBK];
  const int t = threadIdx.x;
  const int n0 = blockIdx.x * FBN, m0 = blockIdx.y * FBM;
  const int wid = t >> 6, lane = t & 63;
  const int wr = wid >> 1, wc = wid & 1;
  const int lr = lane & 15, lk = lane >> 4;
  f4 acc[4][4] = {};
  const int c = t & 127, rbase = t >> 7;
  const int segA = t & 7, rowbA = t >> 3;
  const int nK = K / FBK;
  for (int kt = 0; kt < nK; ++kt) {
    const int k0 = kt * FBK;
    __syncthreads();
    #pragma unroll
    for (int p = 0; p < 4; ++p) {
      int row = rowbA + p * 32;
      const float4* src = (const float4*)(x + (size_t)(m0 + row) * K + k0 + segA * 8);
      float4 f0 = src[0], f1 = src[1];
      uint4 w;
      w.x = f2bf(f0.x) | (f2bf(f0.y) << 16);
      w.y = f2bf(f0.z) | (f2bf(f0.w) << 16);
      w.z = f2bf(f1.x) | (f2bf(f1.y) << 16);
      w.w = f2bf(f1.z) | (f2bf(f1.w) << 16);
      unsigned off = (unsigned)(row * (FBK * 2) + segA * 16) ^ ((row & 7) << 4);
      *(uint4*)((char*)sA + off) = w;
    }
    {
      const int g = k0 >> 7;
      const unsigned zq = (unsigned)qzeros[g * (N >> 3) + ((n0 + c) >> 3)];
      const int   zp = (int)((zq >> (4 * ((n0 + c) & 7))) & 0xFu) + 1;
      const float sc2 = scales[(size_t)g * N + n0 + c];
      #pragma unroll
      for (int p = 0; p < 4; ++p) {
        int r = rbase + p * 2;
        unsigned uq = (unsigned)qweight[(size_t)(kt * 8 + r) * N + n0 + c];
        uint4 w;
        #pragma unroll
        for (int h = 0; h < 4; ++h) {
          int v0 = (int)((uq >> (8 * h))     & 0xFu) - zp;
          int v1 = (int)((uq >> (8 * h + 4)) & 0xFu) - zp;
          ((unsigned*)&w)[h] = f2bf((float)v0 * sc2) | (f2bf((float)v1 * sc2) << 16);
        }
        unsigned off = (unsigned)(c * (FBK * 2) + r * 16) ^ ((c & 7) << 4);
        *(uint4*)((char*)sB + off) = w;
      }
    }
    __syncthreads();
    #pragma unroll
    for (int ks = 0; ks < 2; ++ks) {
      bf8 a[4], b[4];
      #pragma unroll
      for (int mi = 0; mi < 4; ++mi) {
        int row = wr * 64 + mi * 16 + lr;
        unsigned off = (unsigned)(row * (FBK * 2) + ks * 64 + lk * 16) ^ ((row & 7) << 4);
        a[mi] = *(const bf8*)((const char*)sA + off);
      }
      #pragma unroll
      for (int ni = 0; ni < 4; ++ni) {
        int rowN = wc * 64 + ni * 16 + lr;
        unsigned off = (unsigned)(rowN * (FBK * 2) + ks * 64 + lk * 16) ^ ((rowN & 7) << 4);
        b[ni] = *(const bf8*)((const char*)sB + off);
      }
      #pragma unroll
      for (int mi = 0; mi < 4; ++mi)
        #pragma unroll
        for (int ni = 0; ni < 4; ++ni)
          acc[mi][ni] = __builtin_amdgcn_mfma_f32_16x16x32_bf16(a[mi], b[ni], acc[mi][ni], 0, 0, 0);
    }
  }
  #pragma unroll
  for (int ni = 0; ni < 4; ++ni) {
    int col = n0 + wc * 64 + ni * 16 + lr;
    float bv = bias[col];
    #pragma unroll
    for (int mi = 0; mi < 4; ++mi) {
      int row = m0 + wr * 64 + mi * 16 + lk * 4;
      #pragma unroll
      for (int r = 0; r < 4; ++r)
        out[(size_t)(row + r) * N + col] = acc[mi][ni][r] + bv;
    }
  }
}

extern "C" void kernel_launch(void* const* d_in, const int* in_sizes, int n_in,
                              void* d_out, int out_size, void* d_ws, size_t ws_size,
                              hipStream_t stream) {
  const float* x  = (const float*)d_in[0];
  const int*   qw = (const int*)d_in[1];
  const int*   qz = (const int*)d_in[2];
  const float* sc = (const float*)d_in[3];
  const float* bs = (const float*)d_in[4];
  float* out = (float*)d_out;

  const int N = in_sizes[4];
  const int K = (int)(((long long)in_sizes[1] * 8) / N);
  const int M = (int)((long long)in_sizes[0] / K);
  const int n_groups   = (int)((long long)in_sizes[3] / N);
  const int group_size = K / n_groups;

  const size_t need = ((size_t)M * K + (size_t)N * K) * 2;
  if (ws_size >= need && (M % BM) == 0 && (N % BN) == 0 && (K % BK) == 0 &&
      ((M / BM) * (N / BN)) % 8 == 0) {
    unsigned short* xb = (unsigned short*)d_ws;          // [M][K] bf16
    unsigned short* wt = xb + (size_t)M * K;             // [N][K] bf16

    int n16 = M * K / 8;
    cvt_x<<<(n16 + 255) / 256, 256, 0, stream>>>((const float4*)x, (uint4*)xb, n16);

    int ndq = N * (K / 64);
    dq_w<<<(ndq + 255) / 256, 256, 0, stream>>>(qw, qz, sc, wt, N, K, group_size);

    dim3 grid(N / BN, M / BM);
    gemm_tlp2<<<grid, 256, 0, stream>>>(xb, wt, bs, out, M, N, K);
  } else {
    dim3 grid(N / FBN, M / FBM);
    woq_gemm<<<grid, 256, 0, stream>>>(x, qw, qz, sc, bs, out, M, N, K);
  }
}

// Round 19
// 284.051 us; speedup vs baseline: 1.3128x; 1.3128x over previous
//
#include <hip/hip_runtime.h>
#include <hip/hip_bf16.h>
#include <stdint.h>

typedef __bf16 bf8 __attribute__((ext_vector_type(8)));
typedef float  f4  __attribute__((ext_vector_type(4)));

__device__ __forceinline__ unsigned f2bf(float f) {
  union { float f; unsigned u; } v; v.f = f;
  return (v.u + 0x7FFFu + ((v.u >> 16) & 1u)) >> 16;  // RNE f32->bf16
}

// async global->LDS, 16B/lane; LDS dest = wave-uniform base + lane*16
__device__ __forceinline__ void gload_lds16(const void* g, void* l) {
  __builtin_amdgcn_global_load_lds(
      (const __attribute__((address_space(1))) void*)(uintptr_t)g,
      (__attribute__((address_space(3))) void*)(uint32_t)(uintptr_t)l,
      16, 0, 0);
}

// ---------------- pass 1a: x f32 -> bf16 ----------------
__global__ void cvt_x(const float4* __restrict__ x, uint4* __restrict__ xb, int n16) {
  int i = blockIdx.x * blockDim.x + threadIdx.x;
  if (i >= n16) return;
  float4 f0 = x[2 * i], f1 = x[2 * i + 1];
  uint4 w;
  w.x = f2bf(f0.x) | (f2bf(f0.y) << 16);
  w.y = f2bf(f0.z) | (f2bf(f0.w) << 16);
  w.z = f2bf(f1.x) | (f2bf(f1.y) << 16);
  w.w = f2bf(f1.z) | (f2bf(f1.w) << 16);
  xb[i] = w;
}

// ---------------- pass 1b: dequant qweight -> W^T bf16 [N][K] ----------------
__global__ void dq_w(const int* __restrict__ qw, const int* __restrict__ qz,
                     const float* __restrict__ sc, unsigned short* __restrict__ wt,
                     int N, int K, int group_size) {
  int id = blockIdx.x * blockDim.x + threadIdx.x;  // N*K/64 threads
  int n  = id % N;
  int kb = id / N;                  // 64-k block
  if (kb >= K / 64) return;
  int g = (kb * 64) / group_size;
  unsigned zq = ((unsigned)qz[g * (N >> 3) + (n >> 3)] >> (4 * (n & 7))) & 0xFu;
  float zs = (float)(int)(zq + 1u);
  float s  = sc[(size_t)g * N + n];
  #pragma unroll
  for (int r = 0; r < 8; ++r) {
    unsigned q = (unsigned)qw[(size_t)(kb * 8 + r) * N + n];
    uint4 w;
    #pragma unroll
    for (int h = 0; h < 4; ++h) {
      float v0 = (float)(int)((q >> (8 * h))     & 0xFu) - zs;
      float v1 = (float)(int)((q >> (8 * h + 4)) & 0xFu) - zs;
      ((unsigned*)&w)[h] = f2bf(v0 * s) | (f2bf(v1 * s) << 16);
    }
    *(uint4*)(wt + (size_t)n * K + kb * 64 + r * 8) = w;
  }
}

// ---------------- pass 2: 256^2 bf16 GEMM (r13 K-loop + r17 epilogue) -------
// Final configuration (best of 19 rounds, 284us total): 256^2 tile, 8 waves,
// conflict-free rotated-subtile LDS, 2-window deep-covered-drain K-loop,
// LDS-transposed vectorized epilogue (exact 131MB write).
#define BM 256
#define BN 256
#define BK 64

#define SGB(mask, n) __builtin_amdgcn_sched_group_barrier((mask), (n), 0)
#define M_MFMA 0x8
#define M_DSRD 0x100

__launch_bounds__(512, 2)
__global__ void gemm_2wd(const unsigned short* __restrict__ A,  // [M][K] bf16
                         const unsigned short* __restrict__ B,  // [N][K] bf16
                         const float* __restrict__ bias,
                         float* __restrict__ out,
                         int M, int N, int K) {
  __shared__ __align__(16) char smem[131072];

  const int nbx = N / BN;
  const int nwg = (M / BM) * nbx;
  const int id  = blockIdx.y * gridDim.x + blockIdx.x;
  const int cpx = nwg >> 3;                       // nwg % 8 == 0
  const int swzid = (id & 7) * cpx + (id >> 3);   // XCD-contiguous chunks
  const int m0 = (swzid / nbx) * BM;
  const int n0 = (swzid % nbx) * BN;

  const int t    = threadIdx.x;
  const int wid  = t >> 6, lane = t & 63;
  const int wr   = wid >> 2, wc = wid & 3;        // 2(M) x 4(N) waves
  const int lr   = lane & 15, lk = lane >> 4;
  // permuted frag-read offset within a 1024B subtile (round-4, conflict-free)
  const unsigned loff = (unsigned)(lr * 64 + (((lk + (lr >> 1)) & 3) << 4));

  const int srow = lane >> 2;                          // staging row in subtile
  const int scol = (((lane & 3) - (lane >> 3)) & 3) * 8;  // permuted src chunk

  f4 acc[8][4] = {};
  bf8 aL[4][2], aH[4][2], b01[2][2], b23[2][2];

  const int nK = K / BK;
  const int ra = wr * 8;   // A row-group base
  const int rb = wc * 4;   // B row-group base

#define STAGE_A(tile, h)                                                          \
  {                                                                               \
    const int _tt = (tile);                                                       \
    _Pragma("unroll")                                                             \
    for (int cg = 0; cg < 2; ++cg) {                                              \
      const unsigned short* _src = A + (size_t)(m0 + (h) * 128 + wid * 16 + srow) * K \
                                     + _tt * BK + cg * 32 + scol;                 \
      char* _dst = smem + (_tt & 1) * 65536 + ((((h) * 8 + wid) * 2 + cg) << 10); \
      gload_lds16(_src, _dst);                                                    \
    }                                                                             \
  }
#define STAGE_B(tile, h)                                                          \
  {                                                                               \
    const int _tt = (tile);                                                       \
    _Pragma("unroll")                                                             \
    for (int cg = 0; cg < 2; ++cg) {                                              \
      const unsigned short* _src = B + (size_t)(n0 + (h) * 128 + wid * 16 + srow) * K \
                                     + _tt * BK + cg * 32 + scol;                 \
      char* _dst = smem + (_tt & 1) * 65536 + 32768 +                             \
                   ((((h) * 8 + wid) * 2 + cg) << 10);                            \
      gload_lds16(_src, _dst);                                                    \
    }                                                                             \
  }
#define RD(p, slot) (*(const bf8*)((p) + ((unsigned)(slot) << 10) + loff))

  // Prologue: stage tile0 AND tile1 fully (16 loads/wave); drain; barrier;
  // preload aL(0), b01(0).
  STAGE_A(0, 0); STAGE_B(0, 0); STAGE_A(0, 1); STAGE_B(0, 1);
  if (nK > 1) { STAGE_A(1, 0); STAGE_B(1, 0); STAGE_A(1, 1); STAGE_B(1, 1); }
  asm volatile("s_waitcnt vmcnt(0)" ::: "memory");
  __builtin_amdgcn_s_barrier();
  __builtin_amdgcn_sched_barrier(0);
  {
    const char* pA = smem;
    const char* pB = smem + 32768;
    #pragma unroll
    for (int mf = 0; mf < 4; ++mf)
      #pragma unroll
      for (int ks = 0; ks < 2; ++ks)
        aL[mf][ks] = RD(pA, (ra + mf) * 2 + ks);
    #pragma unroll
    for (int nf = 0; nf < 2; ++nf)
      #pragma unroll
      for (int ks = 0; ks < 2; ++ks)
        b01[nf][ks] = RD(pB, (rb + nf) * 2 + ks);
  }

  for (int kt = 0; kt < nK; ++kt) {
    const char* pA = smem + (kt & 1) * 65536;
    const char* pB = pA + 32768;
    const int nxt = (kt + 1 < nK) ? (kt + 1) : kt;   // clamp: stale-but-safe
    const char* qA = smem + (nxt & 1) * 65536;
    const char* qB = qA + 32768;

    // ================= W01: NO staging; read b23+aH(12); MFMA aLx{b01,b23};
    //                   vmcnt(0) (covered >=1400cyc) BEFORE barrier ==========
    __builtin_amdgcn_s_setprio(1);
    #pragma unroll
    for (int nf = 0; nf < 2; ++nf)
      #pragma unroll
      for (int ks = 0; ks < 2; ++ks)
        b23[nf][ks] = RD(pB, (rb + 2 + nf) * 2 + ks);
    #pragma unroll
    for (int mf = 0; mf < 4; ++mf)
      #pragma unroll
      for (int ks = 0; ks < 2; ++ks)
        aH[mf][ks] = RD(pA, (ra + 4 + mf) * 2 + ks);
    #pragma unroll
    for (int mf = 0; mf < 4; ++mf)
      #pragma unroll
      for (int nf = 0; nf < 2; ++nf)
        #pragma unroll
        for (int ks = 0; ks < 2; ++ks)
          acc[mf][nf] = __builtin_amdgcn_mfma_f32_16x16x32_bf16(aL[mf][ks], b01[nf][ks], acc[mf][nf], 0, 0, 0);
    #pragma unroll
    for (int mf = 0; mf < 4; ++mf)
      #pragma unroll
      for (int nf = 0; nf < 2; ++nf)
        #pragma unroll
        for (int ks = 0; ks < 2; ++ks)
          acc[mf][2 + nf] = __builtin_amdgcn_mfma_f32_16x16x32_bf16(aL[mf][ks], b23[nf][ks], acc[mf][2 + nf], 0, 0, 0);
    #pragma unroll
    for (int r = 0; r < 4; ++r) { SGB(M_DSRD, 3); SGB(M_MFMA, 4); }
    __builtin_amdgcn_s_setprio(0);
    asm volatile("s_waitcnt vmcnt(0)" ::: "memory");  // own DMAs from W23(kt-1)
    __builtin_amdgcn_s_barrier();
    __builtin_amdgcn_sched_barrier(0);

    // ================= W23: stage A(kt+2)+B(kt+2) (8 gloads); read aL'/b01'
    //                   of kt+1; MFMA aHxb01 (before b01' reads), aHxb23 =====
    if (kt + 2 < nK) {
      STAGE_A(kt + 2, 0); STAGE_B(kt + 2, 0);
      STAGE_A(kt + 2, 1); STAGE_B(kt + 2, 1);
    }
    __builtin_amdgcn_s_setprio(1);
    #pragma unroll
    for (int mf = 0; mf < 4; ++mf)
      #pragma unroll
      for (int ks = 0; ks < 2; ++ks)
        aL[mf][ks] = RD(qA, (ra + mf) * 2 + ks);
    #pragma unroll
    for (int mf = 0; mf < 4; ++mf)
      #pragma unroll
      for (int nf = 0; nf < 2; ++nf)
        #pragma unroll
        for (int ks = 0; ks < 2; ++ks)
          acc[4 + mf][nf] = __builtin_amdgcn_mfma_f32_16x16x32_bf16(aH[mf][ks], b01[nf][ks], acc[4 + mf][nf], 0, 0, 0);
    #pragma unroll
    for (int nf = 0; nf < 2; ++nf)
      #pragma unroll
      for (int ks = 0; ks < 2; ++ks)
        b01[nf][ks] = RD(qB, (rb + nf) * 2 + ks);
    #pragma unroll
    for (int mf = 0; mf < 4; ++mf)
      #pragma unroll
      for (int nf = 0; nf < 2; ++nf)
        #pragma unroll
        for (int ks = 0; ks < 2; ++ks)
          acc[4 + mf][2 + nf] = __builtin_amdgcn_mfma_f32_16x16x32_bf16(aH[mf][ks], b23[nf][ks], acc[4 + mf][2 + nf], 0, 0, 0);
    #pragma unroll
    for (int r = 0; r < 4; ++r) { SGB(M_DSRD, 3); SGB(M_MFMA, 4); }
    __builtin_amdgcn_s_setprio(0);
    __builtin_amdgcn_s_barrier();
    __builtin_amdgcn_sched_barrier(0);
  }

  // ---- epilogue (r17): LDS-transposed, vectorized C-write ----
  // Wave-private 16KB scratch; per 32-row chunk: write acc+bias into padded
  // [32][68] f32 (writes 2 lanes/bank = free), read back row-major float4
  // (256B/quarter = 2-way = free), store dwordx4 (256B-contiguous rows).
  {
    float* lds_f = (float*)(smem + wid * 16384);
    float bv[4];
    #pragma unroll
    for (int ni = 0; ni < 4; ++ni)
      bv[ni] = bias[n0 + wc * 64 + ni * 16 + lr];

    #pragma unroll
    for (int c = 0; c < 4; ++c) {           // 4 chunks of 32 rows
      #pragma unroll
      for (int m2 = 0; m2 < 2; ++m2) {
        const int mi = c * 2 + m2;
        #pragma unroll
        for (int ni = 0; ni < 4; ++ni) {
          const int col  = ni * 16 + lr;
          const int rowb = m2 * 16 + lk * 4;
          #pragma unroll
          for (int r = 0; r < 4; ++r)
            lds_f[(rowb + r) * 68 + col] = acc[mi][ni][r] + bv[ni];
        }
      }
      // wave-local: compiler orders LDS read-after-write via aliasing
      #pragma unroll
      for (int it = 0; it < 8; ++it) {
        const int row  = it * 4 + (lane >> 4);
        const int col4 = (lane & 15) * 4;
        float4 v = *(float4*)&lds_f[row * 68 + col4];
        const int grow = m0 + wr * 128 + c * 32 + row;
        const int gcol = n0 + wc * 64 + col4;
        *(float4*)&out[(size_t)grow * N + gcol] = v;
      }
    }
  }
#undef STAGE_A
#undef STAGE_B
#undef RD
}

// ---------------- fallback (ws too small): round-1 fused kernel ----------------
#define FBM 128
#define FBN 128
#define FBK 64
__launch_bounds__(256, 2)
__global__ void woq_gemm(const float* __restrict__ x,
                         const int*   __restrict__ qweight,
                         const int*   __restrict__ qzeros,
                         const float* __restrict__ scales,
                         const float* __restrict__ bias,
                         float*       __restrict__ out,
                         int M, int N, int K) {
  __shared__ unsigned short sA[FBM * FBK];
  __shared__ unsigned short sB[FBN * FBK];
  const int t = threadIdx.x;
  const int n0 = blockIdx.x * FBN, m0 = blockIdx.y * FBM;
  const int wid = t >> 6, lane = t & 63;
  const int wr = wid >> 1, wc = wid & 1;
  const int lr = lane & 15, lk = lane >> 4;
  f4 acc[4][4] = {};
  const int c = t & 127, rbase = t >> 7;
  const int segA = t & 7, rowbA = t >> 3;
  const int nK = K / FBK;
  for (int kt = 0; kt < nK; ++kt) {
    const int k0 = kt * FBK;
    __syncthreads();
    #pragma unroll
    for (int p = 0; p < 4; ++p) {
      int row = rowbA + p * 32;
      const float4* src = (const float4*)(x + (size_t)(m0 + row) * K + k0 + segA * 8);
      float4 f0 = src[0], f1 = src[1];
      uint4 w;
      w.x = f2bf(f0.x) | (f2bf(f0.y) << 16);
      w.y = f2bf(f0.z) | (f2bf(f0.w) << 16);
      w.z = f2bf(f1.x) | (f2bf(f1.y) << 16);
      w.w = f2bf(f1.z) | (f2bf(f1.w) << 16);
      unsigned off = (unsigned)(row * (FBK * 2) + segA * 16) ^ ((row & 7) << 4);
      *(uint4*)((char*)sA + off) = w;
    }
    {
      const int g = k0 >> 7;
      const unsigned zq = (unsigned)qzeros[g * (N >> 3) + ((n0 + c) >> 3)];
      const int   zp = (int)((zq >> (4 * ((n0 + c) & 7))) & 0xFu) + 1;
      const float sc2 = scales[(size_t)g * N + n0 + c];
      #pragma unroll
      for (int p = 0; p < 4; ++p) {
        int r = rbase + p * 2;
        unsigned uq = (unsigned)qweight[(size_t)(kt * 8 + r) * N + n0 + c];
        uint4 w;
        #pragma unroll
        for (int h = 0; h < 4; ++h) {
          int v0 = (int)((uq >> (8 * h))     & 0xFu) - zp;
          int v1 = (int)((uq >> (8 * h + 4)) & 0xFu) - zp;
          ((unsigned*)&w)[h] = f2bf((float)v0 * sc2) | (f2bf((float)v1 * sc2) << 16);
        }
        unsigned off = (unsigned)(c * (FBK * 2) + r * 16) ^ ((c & 7) << 4);
        *(uint4*)((char*)sB + off) = w;
      }
    }
    __syncthreads();
    #pragma unroll
    for (int ks = 0; ks < 2; ++ks) {
      bf8 a[4], b[4];
      #pragma unroll
      for (int mi = 0; mi < 4; ++mi) {
        int row = wr * 64 + mi * 16 + lr;
        unsigned off = (unsigned)(row * (FBK * 2) + ks * 64 + lk * 16) ^ ((row & 7) << 4);
        a[mi] = *(const bf8*)((const char*)sA + off);
      }
      #pragma unroll
      for (int ni = 0; ni < 4; ++ni) {
        int rowN = wc * 64 + ni * 16 + lr;
        unsigned off = (unsigned)(rowN * (FBK * 2) + ks * 64 + lk * 16) ^ ((rowN & 7) << 4);
        b[ni] = *(const bf8*)((const char*)sB + off);
      }
      #pragma unroll
      for (int mi = 0; mi < 4; ++mi)
        #pragma unroll
        for (int ni = 0; ni < 4; ++ni)
          acc[mi][ni] = __builtin_amdgcn_mfma_f32_16x16x32_bf16(a[mi], b[ni], acc[mi][ni], 0, 0, 0);
    }
  }
  #pragma unroll
  for (int ni = 0; ni < 4; ++ni) {
    int col = n0 + wc * 64 + ni * 16 + lr;
    float bv = bias[col];
    #pragma unroll
    for (int mi = 0; mi < 4; ++mi) {
      int row = m0 + wr * 64 + mi * 16 + lk * 4;
      #pragma unroll
      for (int r = 0; r < 4; ++r)
        out[(size_t)(row + r) * N + col] = acc[mi][ni][r] + bv;
    }
  }
}

extern "C" void kernel_launch(void* const* d_in, const int* in_sizes, int n_in,
                              void* d_out, int out_size, void* d_ws, size_t ws_size,
                              hipStream_t stream) {
  const float* x  = (const float*)d_in[0];
  const int*   qw = (const int*)d_in[1];
  const int*   qz = (const int*)d_in[2];
  const float* sc = (const float*)d_in[3];
  const float* bs = (const float*)d_in[4];
  float* out = (float*)d_out;

  const int N = in_sizes[4];
  const int K = (int)(((long long)in_sizes[1] * 8) / N);
  const int M = (int)((long long)in_sizes[0] / K);
  const int n_groups   = (int)((long long)in_sizes[3] / N);
  const int group_size = K / n_groups;

  const size_t need = ((size_t)M * K + (size_t)N * K) * 2;
  if (ws_size >= need && (M % BM) == 0 && (N % BN) == 0 && (K % BK) == 0 &&
      ((M / BM) * (N / BN)) % 8 == 0) {
    unsigned short* xb = (unsigned short*)d_ws;          // [M][K] bf16
    unsigned short* wt = xb + (size_t)M * K;             // [N][K] bf16

    int n16 = M * K / 8;
    cvt_x<<<(n16 + 255) / 256, 256, 0, stream>>>((const float4*)x, (uint4*)xb, n16);

    int ndq = N * (K / 64);
    dq_w<<<(ndq + 255) / 256, 256, 0, stream>>>(qw, qz, sc, wt, N, K, group_size);

    dim3 grid(N / BN, M / BM);
    gemm_2wd<<<grid, 512, 0, stream>>>(xb, wt, bs, out, M, N, K);
  } else {
    dim3 grid(N / FBN, M / FBM);
    woq_gemm<<<grid, 256, 0, stream>>>(x, qw, qz, sc, bs, out, M, N, K);
  }
}